// Round 2
// baseline (319.553 us; speedup 1.0000x reference)
//
#include <hip/hip_runtime.h>

// Masked cumulative sum along dim=1. x:(256,131072) f32, mask int32, out f32.
//
// One block per row (256 blocks = 1/CU), 1024 threads (16 waves).
// VPT=16 elements/thread -> tile = 16384, only 8 tiles/row: the expensive
// per-tile machinery (6-step ds_bpermute shfl scan + barrier + LDS combine)
// is paid 8x instead of 32x; the serial thread scan of 16 contiguous
// elements is cheap VALU. Next tile's 8 vector loads (128 KiB/CU in flight)
// are issued right after the current tile's values are consumed, so the
// compiler-inserted vmcnt(0) at __syncthreads overlaps with the scan.

#define N_ROWS   256
#define N_COLS   131072
#define BLOCK    1024
#define VPT      16                  // elements per thread per tile
#define NV4      (VPT / 4)           // 4 float4 + 4 int4 loads per thread
#define TILE     (BLOCK * VPT)       // 16384
#define NTILES   (N_COLS / TILE)     // 8
#define NWAVES   (BLOCK / 64)        // 16

__global__ __launch_bounds__(BLOCK, 4)
void masked_cumsum_kernel(const float* __restrict__ x,
                          const int* __restrict__ mask,
                          float* __restrict__ out) {
    __shared__ float waveSums[2][NWAVES];

    const int tid  = threadIdx.x;
    const int lane = tid & 63;
    const int wave = tid >> 6;

    const size_t rowBase = (size_t)blockIdx.x * N_COLS;
    const float4* __restrict__ x4 = (const float4*)(x + rowBase);
    const int4*   __restrict__ m4 = (const int4*)(mask + rowBase);
    float4*       __restrict__ o4 = (float4*)(out + rowBase);

    float carry = 0.0f;

    // Prefetch tile 0 (blocked layout: thread owns 16 contiguous elements).
    float4 xa[NV4];
    int4   ma[NV4];
    #pragma unroll
    for (int k = 0; k < NV4; ++k) {
        xa[k] = x4[tid * NV4 + k];
        ma[k] = m4[tid * NV4 + k];
    }

    for (int t = 0; t < NTILES; ++t) {
        // Consume current tile into the running thread-local scan, freeing
        // xa/ma for the next prefetch (keeps VGPR count ~65, no spills).
        float s[VPT];
        float run = 0.0f;
        #pragma unroll
        for (int k = 0; k < NV4; ++k) {
            run += ma[k].x ? xa[k].x : 0.0f; s[4*k+0] = run;
            run += ma[k].y ? xa[k].y : 0.0f; s[4*k+1] = run;
            run += ma[k].z ? xa[k].z : 0.0f; s[4*k+2] = run;
            run += ma[k].w ? xa[k].w : 0.0f; s[4*k+3] = run;
        }
        const float tsum = run;

        // Issue next tile's loads now — they fly during the shfl scan,
        // barrier, and store below.
        if (t + 1 < NTILES) {
            const int nb = (t + 1) * BLOCK * NV4 + tid * NV4;
            #pragma unroll
            for (int k = 0; k < NV4; ++k) {
                xa[k] = x4[nb + k];
                ma[k] = m4[nb + k];
            }
        }

        // Wave-level inclusive scan over 64 lanes.
        float incl = tsum;
        #pragma unroll
        for (int d = 1; d < 64; d <<= 1) {
            const float y = __shfl_up(incl, d, 64);
            if (lane >= d) incl += y;
        }
        const float waveExcl = incl - tsum;

        if (lane == 63) waveSums[t & 1][wave] = incl;
        __syncthreads();

        // Block combine: exclusive wave offset + tile total.
        float waveOff = 0.0f, tileTot = 0.0f;
        #pragma unroll
        for (int w = 0; w < NWAVES; ++w) {
            const float v = waveSums[t & 1][w];
            if (w < wave) waveOff += v;
            tileTot += v;
        }

        const float base = carry + waveOff + waveExcl;
        const int ob = t * BLOCK * NV4 + tid * NV4;
        #pragma unroll
        for (int k = 0; k < NV4; ++k) {
            float4 r;
            r.x = base + s[4*k+0];
            r.y = base + s[4*k+1];
            r.z = base + s[4*k+2];
            r.w = base + s[4*k+3];
            o4[ob + k] = r;
        }

        carry += tileTot;
        // Single barrier per tile: waveSums is parity double-buffered; the
        // barrier in iteration t+1 orders reads(t) before writes(t+2).
    }
}

extern "C" void kernel_launch(void* const* d_in, const int* in_sizes, int n_in,
                              void* d_out, int out_size, void* d_ws, size_t ws_size,
                              hipStream_t stream) {
    const float* x    = (const float*)d_in[0];
    const int*   mask = (const int*)d_in[1];
    float*       out  = (float*)d_out;
    (void)in_sizes; (void)n_in; (void)out_size; (void)d_ws; (void)ws_size;

    masked_cumsum_kernel<<<N_ROWS, BLOCK, 0, stream>>>(x, mask, out);
}